// Round 8
// baseline (450.407 us; speedup 1.0000x reference)
//
#include <hip/hip_runtime.h>

#define NT    262144
#define SDIM  32
#define NSEG  1024           // speculative segments; one WAVE runs TWO segments
#define SEG   (NT / NSEG)    // 256 steps per segment
#define WARM  192            // warm-up steps; WARM < SEG => warm windows disjoint
#define EPSV  1e-12f
#define L2E   1.4426950408889634f   // log2(e)
#define LN2   0.6931471805599453f
// warm-window copies in d_ws: NSEG windows (seg 0 = dummy) of WARM rows x 32
#define WSW   ((size_t)NSEG * WARM * SDIM)
#define WS_NEEDED (2 * WSW * 4)

// keep a value in a VGPR and make it opaque to remat (defeats the
// "invariant-load rematerialization is free" heuristic that was re-loading
// every weight from L1 inside the step loop in rounds 6/7)
#define PIN(X_) asm volatile("" : "+v"(X_))

// ---------------------------------------------------------------------------
// Kernel 1: precompute v-independent gate terms, PRE-SCALED for exp2 sigmoids:
//   glN = -log2e*(X@gate_beta), rlN likewise -> out_z / out_cand regions.
// Also writes race-free warm-window copies into d_ws (window s = steps
// [s*SEG-WARM, s*SEG) for s>=1; window 0 = steps [0,WARM), dummy for seg 0).
// ---------------------------------------------------------------------------
__global__ void precompute_lin(const float* __restrict__ X,
                               const float* __restrict__ gb,
                               const float* __restrict__ rg,
                               float* __restrict__ glN,
                               float* __restrict__ rlN,
                               float* __restrict__ wsgl,   // may be null
                               float* __restrict__ wsrl)
{
    int idx = blockIdx.x * blockDim.x + threadIdx.x;   // = t*32 + i
    int t = idx >> 5, i = idx & 31;
    const float* xr = X + (size_t)t * 32;
    float a = 0.f, b = 0.f;
#pragma unroll
    for (int j = 0; j < 32; ++j) {
        float xv = xr[j];
        a = fmaf(xv, gb[j * 32 + i], a);
        b = fmaf(xv, rg[j * 32 + i], b);
    }
    a *= -L2E;  b *= -L2E;
    glN[idx] = a;
    rlN[idx] = b;
    if (wsgl) {
        int m  = t % SEG;
        int s1 = t / SEG + 1;
        if (m >= SEG - WARM && s1 < NSEG) {
            size_t o = ((size_t)s1 * WARM + (m - (SEG - WARM))) * SDIM + i;
            wsgl[o] = a;  wsrl[o] = b;
        }
        if (t < WARM) {                        // window 0 (dummy, seg 0)
            size_t o = (size_t)t * SDIM + i;
            wsgl[o] = a;  wsrl[o] = b;
        }
    }
}

// DPP partial-sum add (row_shr / row_bcast chain; total lands in lane 63)
#define DPP_ADD(S_, CTRL_)                                                     \
{   int t__ = __builtin_amdgcn_update_dpp(0, __builtin_bit_cast(int, (S_)),    \
                                          (CTRL_), 0xF, 0xF, true);            \
    (S_) += __builtin_bit_cast(float, t__); }

// ---------------------------------------------------------------------------
// Fused step: advances TWO independent recurrences (A and B) in one wave.
// The two dependency chains interleave, hiding LDS / transcendental latency.
// TIA_/TIB_ evaluated FIRST (macro hygiene). W2 is a HALF-dot per lane
// (cols (half*32)..+31) combined with shfl_xor(32) -> w2r needs only 32 regs.
// ---------------------------------------------------------------------------
#define STEP2(TIA_, TIB_, GLA_, RLA_, RA_, GLB_, RLB_, RB_, DOSTORE_)          \
{                                                                              \
    const int tiA_ = (TIA_);                                                   \
    const int tiB_ = (TIB_);                                                   \
    float rsA_ = __builtin_amdgcn_rcpf(                                        \
                     1.f + __builtin_amdgcn_exp2f(fmaf(rswN, vA, (RLA_))));    \
    float rsB_ = __builtin_amdgcn_rcpf(                                        \
                     1.f + __builtin_amdgcn_exp2f(fmaf(rswN, vB, (RLB_))));    \
    float rvA_ = rsA_ * vA;                                                    \
    float rvB_ = rsB_ * vB;                                                    \
    smA[(half << 6) + i] = half ? rvB_ : rvA_;   /* A->[0..31], B->[64..95] */ \
    __builtin_amdgcn_wave_barrier();                                           \
    float zargA_ = fmaf(gswN, vA, (GLA_));                                     \
    float zargB_ = fmaf(gswN, vB, (GLB_));                                     \
    float hA0_ = b1l, hB0_ = b1l;                                              \
    hA0_ = fmaf(w1r[0], (RA_), hA0_);                                          \
    hB0_ = fmaf(w1r[0], (RB_), hB0_);                                          \
    hA0_ = fmaf(w1r[1], fabsf((RA_)), hA0_);                                   \
    hB0_ = fmaf(w1r[1], fabsf((RB_)), hB0_);                                   \
    hA0_ = fmaf(w1r[2], (RA_) * (RA_), hA0_);                                  \
    hB0_ = fmaf(w1r[2], (RB_) * (RB_), hB0_);                                  \
    float hA1_ = 0.f, hA2_ = 0.f, hA3_ = 0.f;                                  \
    float hB1_ = 0.f, hB2_ = 0.f, hB3_ = 0.f;                                  \
    const float4* rvpA_ = (const float4*)smA;                                  \
    const float4* rvpB_ = (const float4*)(smA + 64);                           \
    _Pragma("unroll")                                                          \
    for (int q_ = 0; q_ < 8; ++q_) {                                           \
        float4 xa_ = rvpA_[q_];                                                \
        float4 xb_ = rvpB_[q_];                                                \
        hA0_ = fmaf(w1r[3 + 4 * q_ + 0], xa_.x, hA0_);                         \
        hB0_ = fmaf(w1r[3 + 4 * q_ + 0], xb_.x, hB0_);                         \
        hA1_ = fmaf(w1r[3 + 4 * q_ + 1], xa_.y, hA1_);                         \
        hB1_ = fmaf(w1r[3 + 4 * q_ + 1], xb_.y, hB1_);                         \
        hA2_ = fmaf(w1r[3 + 4 * q_ + 2], xa_.z, hA2_);                         \
        hB2_ = fmaf(w1r[3 + 4 * q_ + 2], xb_.z, hB2_);                         \
        hA3_ = fmaf(w1r[3 + 4 * q_ + 3], xa_.w, hA3_);                         \
        hB3_ = fmaf(w1r[3 + 4 * q_ + 3], xb_.w, hB3_);                         \
    }                                                                          \
    float hpA_ = (hA0_ + hA1_) + (hA2_ + hA3_);                                \
    float hpB_ = (hB0_ + hB1_) + (hB2_ + hB3_);                                \
    float thA_ = fmaf(-2.f, __builtin_amdgcn_rcpf(                             \
                     __builtin_amdgcn_exp2f(hpA_) + 1.f), 1.f);                \
    float thB_ = fmaf(-2.f, __builtin_amdgcn_rcpf(                             \
                     __builtin_amdgcn_exp2f(hpB_) + 1.f), 1.f);                \
    smB[lane] = thA_;                                                          \
    smB[64 + lane] = thB_;                                                     \
    __builtin_amdgcn_wave_barrier();                                           \
    float zA_ = __builtin_amdgcn_rcpf(1.f + __builtin_amdgcn_exp2f(zargA_));   \
    float zB_ = __builtin_amdgcn_rcpf(1.f + __builtin_amdgcn_exp2f(zargB_));   \
    float qA0_ = 0.f, qA1_ = 0.f, qA2_ = 0.f, qA3_ = 0.f;                      \
    float qB0_ = 0.f, qB1_ = 0.f, qB2_ = 0.f, qB3_ = 0.f;                      \
    const float4* hqA_ = (const float4*)(smB + (half << 5));                   \
    const float4* hqB_ = (const float4*)(smB + 64 + (half << 5));              \
    _Pragma("unroll")                                                          \
    for (int q_ = 0; q_ < 8; ++q_) {                                           \
        float4 ca_ = hqA_[q_];                                                 \
        float4 cb_ = hqB_[q_];                                                 \
        qA0_ = fmaf(w2r[4 * q_ + 0], ca_.x, qA0_);                             \
        qB0_ = fmaf(w2r[4 * q_ + 0], cb_.x, qB0_);                             \
        qA1_ = fmaf(w2r[4 * q_ + 1], ca_.y, qA1_);                             \
        qB1_ = fmaf(w2r[4 * q_ + 1], cb_.y, qB1_);                             \
        qA2_ = fmaf(w2r[4 * q_ + 2], ca_.z, qA2_);                             \
        qB2_ = fmaf(w2r[4 * q_ + 2], cb_.z, qB2_);                             \
        qA3_ = fmaf(w2r[4 * q_ + 3], ca_.w, qA3_);                             \
        qB3_ = fmaf(w2r[4 * q_ + 3], cb_.w, qB3_);                             \
    }                                                                          \
    float pA_ = (qA0_ + qA1_) + (qA2_ + qA3_);                                 \
    float pB_ = (qB0_ + qB1_) + (qB2_ + qB3_);                                 \
    pA_ += __shfl_xor(pA_, 32);                                                \
    pB_ += __shfl_xor(pB_, 32);                                                \
    float rawA_ = pA_ + b2l;                                                   \
    float rawB_ = pB_ + b2l;                                                   \
    float eA_ = __builtin_amdgcn_exp2f(-fabsf(rawA_));                         \
    float eB_ = __builtin_amdgcn_exp2f(-fabsf(rawB_));                         \
    float spA_ = fmaxf(rawA_, 0.f) + __builtin_amdgcn_logf(1.f + eA_);         \
    float spB_ = fmaxf(rawB_, 0.f) + __builtin_amdgcn_logf(1.f + eB_);         \
    float candA_ = LN2 * spA_;                                                 \
    float candB_ = LN2 * spB_;                                                 \
    float vnA_ = fmaxf(fmaf(zA_, candA_ - vA, vA), EPSV);                      \
    float vnB_ = fmaxf(fmaf(zB_, candB_ - vB, vB), EPSV);                      \
    if (DOSTORE_) {                                                            \
        out_z  [(size_t)tiA_ * SDIM + i] = zA_;                                \
        out_cand[(size_t)tiA_ * SDIM + i] = candA_;                            \
        out_z  [(size_t)tiB_ * SDIM + i] = zB_;                                \
        out_cand[(size_t)tiB_ * SDIM + i] = candB_;                            \
        float sA_ = vnA_, sB_ = vnB_;                                          \
        DPP_ADD(sA_, 0x111) DPP_ADD(sA_, 0x112) DPP_ADD(sA_, 0x114)            \
        DPP_ADD(sA_, 0x118) DPP_ADD(sA_, 0x142) DPP_ADD(sA_, 0x143)            \
        DPP_ADD(sB_, 0x111) DPP_ADD(sB_, 0x112) DPP_ADD(sB_, 0x114)            \
        DPP_ADD(sB_, 0x118) DPP_ADD(sB_, 0x142) DPP_ADD(sB_, 0x143)            \
        if (lane == 63) {                                                      \
            out_sigma[tiA_] = sA_ * (1.f / 64.f);                              \
            out_sigma[tiB_] = sB_ * (1.f / 64.f);                              \
        }                                                                      \
    }                                                                          \
    vA = vnA_;                                                                 \
    vB = vnB_;                                                                 \
}

// 4-deep software-pipelined dual-segment run. Slot k refilled (step s+k+4)
// right before consumption -> ~4 fused-steps of load-latency cover.
#define PIPE2(GA_, LA_, RA_, GB_, LB_, RB_, NSTEPS_, TA_, TB_, DOSTORE_)       \
{                                                                              \
    float gA0_, gA1_, gA2_, gA3_, lA0_, lA1_, lA2_, lA3_,                      \
          rA0_, rA1_, rA2_, rA3_;                                              \
    float gB0_, gB1_, gB2_, gB3_, lB0_, lB1_, lB2_, lB3_,                      \
          rB0_, rB1_, rB2_, rB3_;                                              \
    gA0_=(GA_)[0*SDIM+i]; lA0_=(LA_)[0*SDIM+i]; rA0_=(RA_)[0];                 \
    gB0_=(GB_)[0*SDIM+i]; lB0_=(LB_)[0*SDIM+i]; rB0_=(RB_)[0];                 \
    gA1_=(GA_)[1*SDIM+i]; lA1_=(LA_)[1*SDIM+i]; rA1_=(RA_)[1];                 \
    gB1_=(GB_)[1*SDIM+i]; lB1_=(LB_)[1*SDIM+i]; rB1_=(RB_)[1];                 \
    gA2_=(GA_)[2*SDIM+i]; lA2_=(LA_)[2*SDIM+i]; rA2_=(RA_)[2];                 \
    gB2_=(GB_)[2*SDIM+i]; lB2_=(LB_)[2*SDIM+i]; rB2_=(RB_)[2];                 \
    gA3_=(GA_)[3*SDIM+i]; lA3_=(LA_)[3*SDIM+i]; rA3_=(RA_)[3];                 \
    gB3_=(GB_)[3*SDIM+i]; lB3_=(LB_)[3*SDIM+i]; rB3_=(RB_)[3];                 \
    for (int s_ = 0; s_ < (NSTEPS_); s_ += 4) {                                \
        int t0_ = s_ + 4; if (t0_ > (NSTEPS_) - 1) t0_ = (NSTEPS_) - 1;        \
        float cgA_=gA0_, clA_=lA0_, crA_=rA0_;                                 \
        float cgB_=gB0_, clB_=lB0_, crB_=rB0_;                                 \
        gA0_=(GA_)[(size_t)t0_*SDIM+i]; lA0_=(LA_)[(size_t)t0_*SDIM+i];        \
        rA0_=(RA_)[t0_];                                                       \
        gB0_=(GB_)[(size_t)t0_*SDIM+i]; lB0_=(LB_)[(size_t)t0_*SDIM+i];        \
        rB0_=(RB_)[t0_];                                                       \
        STEP2((TA_)+s_+0, (TB_)+s_+0, cgA_, clA_, crA_, cgB_, clB_, crB_,      \
              DOSTORE_)                                                        \
        int t1_ = s_ + 5; if (t1_ > (NSTEPS_) - 1) t1_ = (NSTEPS_) - 1;        \
        cgA_=gA1_; clA_=lA1_; crA_=rA1_;                                       \
        cgB_=gB1_; clB_=lB1_; crB_=rB1_;                                       \
        gA1_=(GA_)[(size_t)t1_*SDIM+i]; lA1_=(LA_)[(size_t)t1_*SDIM+i];        \
        rA1_=(RA_)[t1_];                                                       \
        gB1_=(GB_)[(size_t)t1_*SDIM+i]; lB1_=(LB_)[(size_t)t1_*SDIM+i];        \
        rB1_=(RB_)[t1_];                                                       \
        STEP2((TA_)+s_+1, (TB_)+s_+1, cgA_, clA_, crA_, cgB_, clB_, crB_,      \
              DOSTORE_)                                                        \
        int t2_ = s_ + 6; if (t2_ > (NSTEPS_) - 1) t2_ = (NSTEPS_) - 1;        \
        cgA_=gA2_; clA_=lA2_; crA_=rA2_;                                       \
        cgB_=gB2_; clB_=lB2_; crB_=rB2_;                                       \
        gA2_=(GA_)[(size_t)t2_*SDIM+i]; lA2_=(LA_)[(size_t)t2_*SDIM+i];        \
        rA2_=(RA_)[t2_];                                                       \
        gB2_=(GB_)[(size_t)t2_*SDIM+i]; lB2_=(LB_)[(size_t)t2_*SDIM+i];        \
        rB2_=(RB_)[t2_];                                                       \
        STEP2((TA_)+s_+2, (TB_)+s_+2, cgA_, clA_, crA_, cgB_, clB_, crB_,      \
              DOSTORE_)                                                        \
        int t3_ = s_ + 7; if (t3_ > (NSTEPS_) - 1) t3_ = (NSTEPS_) - 1;        \
        cgA_=gA3_; clA_=lA3_; crA_=rA3_;                                       \
        cgB_=gB3_; clB_=lB3_; crB_=rB3_;                                       \
        gA3_=(GA_)[(size_t)t3_*SDIM+i]; lA3_=(LA_)[(size_t)t3_*SDIM+i];        \
        rA3_=(RA_)[t3_];                                                       \
        gB3_=(GB_)[(size_t)t3_*SDIM+i]; lB3_=(LB_)[(size_t)t3_*SDIM+i];        \
        rB3_=(RB_)[t3_];                                                       \
        STEP2((TA_)+s_+3, (TB_)+s_+3, cgA_, clA_, crA_, cgB_, clB_, crB_,      \
              DOSTORE_)                                                        \
    }                                                                          \
}

// ---------------------------------------------------------------------------
// Kernel 2: speculative-parallel scan, TWO segments per wave (A=2b, B=2b+1).
// waves_per_eu(1): pressure target = 1 wave/EU (512-reg budget) so the
// allocator keeps the ~100 weight floats register-resident instead of
// rematerializing L1 loads per step (rounds 6/7 pathology).
// ---------------------------------------------------------------------------
__global__ void __launch_bounds__(64)
__attribute__((amdgpu_waves_per_eu(1)))
scan_kernel(const float* __restrict__ returns,
            const float* __restrict__ gsw,
            const float* __restrict__ rsw,
            const float* __restrict__ W1,     // [64, 35]
            const float* __restrict__ b1,     // [64]
            const float* __restrict__ W2,     // [32, 64]
            const float* __restrict__ b2,     // [32]
            const float* __restrict__ X,      // fallback warm-up only
            const float* __restrict__ gb,
            const float* __restrict__ rg,
            const float* __restrict__ wsgl,   // warm windows (or null)
            const float* __restrict__ wsrl,
            float* __restrict__ out_sigma,    // [N]
            float* __restrict__ out_z,        // [N*32]  (pre-filled glN)
            float* __restrict__ out_cand,     // [N*32]  (pre-filled rlN)
            float* __restrict__ out_vfinal)   // [32]
{
    const int lane = threadIdx.x;
    const int i    = lane & 31;
    const int half = lane >> 5;
    const int bid  = blockIdx.x;
    const int tA   = (2 * bid) * SEG;
    const int tB   = tA + SEG;
    const int wstA = (tA == 0) ? 0 : (tA - WARM);
    const int wstB = tB - WARM;

    __shared__ __align__(16) float smA[128];
    __shared__ __align__(16) float smB[128];
    __shared__ __align__(16) float smGB[32 * 32];   // fallback only
    __shared__ __align__(16) float smRG[32 * 32];   // fallback only

    // ---- static weights, pre-scaled so every transcendental is exp2/log2 ----
    float gswN = -L2E * gsw[i];
    float rswN = -L2E * rsw[i];
    float w1r[35];
#pragma unroll
    for (int j = 0; j < 35; ++j) w1r[j] = (2.f * L2E) * W1[lane * 35 + j];
    float b1l = (2.f * L2E) * b1[lane];
    float w2r[32];                       // half-dot: cols (half*32)..+31
#pragma unroll
    for (int j = 0; j < 32; ++j) w2r[j] = L2E * W2[i * 64 + (half << 5) + j];
    float b2l = L2E * b2[i];

    // pin weights into VGPRs (asm-defined values cannot be rematerialized)
    PIN(gswN); PIN(rswN); PIN(b1l); PIN(b2l);
#pragma unroll
    for (int j = 0; j < 35; ++j) PIN(w1r[j]);
#pragma unroll
    for (int j = 0; j < 32; ++j) PIN(w2r[j]);

    // ---- initial states (warm-start guesses; converge during warm-up) ----
    float rA0 = returns[wstA];
    float rB0 = returns[wstB];
    float vA = rA0 * rA0;
    float vB = rB0 * rB0;

    // ---- warm-up (both segments fused) ----
    if (wsgl) {
        const float* gwA = wsgl + (size_t)(2 * bid) * WARM * SDIM;
        const float* lwA = wsrl + (size_t)(2 * bid) * WARM * SDIM;
        const float* gwB = wsgl + (size_t)(2 * bid + 1) * WARM * SDIM;
        const float* lwB = wsrl + (size_t)(2 * bid + 1) * WARM * SDIM;
        const float* rrA = returns + wstA;
        const float* rrB = returns + wstB;
        PIPE2(gwA, lwA, rrA, gwB, lwB, rrB, WARM, 0, 0, false)
    } else {
        // cold fallback: stage scaled betas in LDS, recompute gl/rl from X
        for (int k = lane; k < 1024; k += 64) {
            smGB[k] = -L2E * gb[k];
            smRG[k] = -L2E * rg[k];
        }
        __syncthreads();
        for (int t = 0; t < WARM; ++t) {
            const float* xA = X + (size_t)(wstA + t) * 32;
            const float* xB = X + (size_t)(wstB + t) * 32;
            float aA = 0.f, cA = 0.f, aB = 0.f, cB = 0.f;
#pragma unroll
            for (int j = 0; j < 32; ++j) {
                float xa = xA[j], xb = xB[j];
                float g_ = smGB[j * 32 + i], r_ = smRG[j * 32 + i];
                aA = fmaf(xa, g_, aA);
                cA = fmaf(xa, r_, cA);
                aB = fmaf(xb, g_, aB);
                cB = fmaf(xb, r_, cB);
            }
            float rca = returns[wstA + t], rcb = returns[wstB + t];
            STEP2(0, 0, aA, cA, rca, aB, cB, rcb, false)
        }
    }

    // segment A of block 0 starts exactly (dummy warm-up discarded)
    if (tA == 0) {
        float r0 = returns[0];
        vA = r0 * r0;
    }

    // ---- owned segments (reads clamped to own range; overwrite in place) ----
    {
        const float* gsA = out_z   + (size_t)tA * SDIM;
        const float* lsA = out_cand + (size_t)tA * SDIM;
        const float* rsA = returns + tA;
        const float* gsB = out_z   + (size_t)tB * SDIM;
        const float* lsB = out_cand + (size_t)tB * SDIM;
        const float* rsB = returns + tB;
        PIPE2(gsA, lsA, rsA, gsB, lsB, rsB, SEG, tA, tB, true)
    }

    if (bid == NSEG / 2 - 1 && lane < SDIM) out_vfinal[i] = vB;
}

// ---------------------------------------------------------------------------
extern "C" void kernel_launch(void* const* d_in, const int* in_sizes, int n_in,
                              void* d_out, int out_size, void* d_ws, size_t ws_size,
                              hipStream_t stream)
{
    const float* X          = (const float*)d_in[0];
    const float* returns    = (const float*)d_in[1];
    const float* gate_beta  = (const float*)d_in[2];
    const float* gsw        = (const float*)d_in[3];
    const float* reset_gamma= (const float*)d_in[4];
    const float* rsw        = (const float*)d_in[5];
    const float* W1         = (const float*)d_in[6];
    const float* b1         = (const float*)d_in[7];
    const float* W2         = (const float*)d_in[8];
    const float* b2         = (const float*)d_in[9];

    float* out       = (float*)d_out;
    float* out_sigma = out;                                   // [N]
    float* out_z     = out + NT;                              // [N*S]
    float* out_cand  = out + NT + (size_t)NT * SDIM;          // [N*S]
    float* out_vfin  = out + NT + 2 * (size_t)NT * SDIM;      // [S]

    const bool use_ws = (ws_size >= WS_NEEDED);
    float* wsgl = use_ws ? (float*)d_ws : nullptr;
    float* wsrl = use_ws ? ((float*)d_ws + WSW) : nullptr;

    precompute_lin<<<(NT * SDIM) / 256, 256, 0, stream>>>(
        X, gate_beta, reset_gamma, out_z, out_cand, wsgl, wsrl);

    scan_kernel<<<NSEG / 2, 64, 0, stream>>>(
        returns, gsw, rsw, W1, b1, W2, b2,
        X, gate_beta, reset_gamma, wsgl, wsrl,
        out_sigma, out_z, out_cand, out_vfin);
}

// Round 9
// 266.178 us; speedup vs baseline: 1.6921x; 1.6921x over previous
//
#include <hip/hip_runtime.h>

#define NT    262144
#define SDIM  32
#define NSEG  2048           // speculative segments; one WAVE runs TWO segments
#define SEG   (NT / NSEG)    // 128 steps per segment
#define WARM  96             // warm-up steps; WARM < SEG => warm windows disjoint
#define EPSV  1e-12f
#define L2E   1.4426950408889634f   // log2(e)
#define LN2   0.6931471805599453f
// warm-window copies in d_ws: NSEG windows (seg 0 = dummy) of WARM rows x 32
#define WSW   ((size_t)NSEG * WARM * SDIM)
#define WS_NEEDED (2 * WSW * 4)

// keep a value in a VGPR and make it opaque to remat
#define PIN(X_) asm volatile("" : "+v"(X_))

// ---------------------------------------------------------------------------
// Kernel 1: precompute v-independent gate terms, PRE-SCALED for exp2 sigmoids:
//   glN = -log2e*(X@gate_beta), rlN likewise -> out_z / out_cand regions.
// Also writes race-free warm-window copies into d_ws (window s = steps
// [s*SEG-WARM, s*SEG) for s>=1; window 0 = steps [0,WARM), dummy for seg 0).
// ---------------------------------------------------------------------------
__global__ void precompute_lin(const float* __restrict__ X,
                               const float* __restrict__ gb,
                               const float* __restrict__ rg,
                               float* __restrict__ glN,
                               float* __restrict__ rlN,
                               float* __restrict__ wsgl,   // may be null
                               float* __restrict__ wsrl)
{
    int idx = blockIdx.x * blockDim.x + threadIdx.x;   // = t*32 + i
    int t = idx >> 5, i = idx & 31;
    const float* xr = X + (size_t)t * 32;
    float a = 0.f, b = 0.f;
#pragma unroll
    for (int j = 0; j < 32; ++j) {
        float xv = xr[j];
        a = fmaf(xv, gb[j * 32 + i], a);
        b = fmaf(xv, rg[j * 32 + i], b);
    }
    a *= -L2E;  b *= -L2E;
    glN[idx] = a;
    rlN[idx] = b;
    if (wsgl) {
        int m  = t % SEG;
        int s1 = t / SEG + 1;
        if (m >= SEG - WARM && s1 < NSEG) {
            size_t o = ((size_t)s1 * WARM + (m - (SEG - WARM))) * SDIM + i;
            wsgl[o] = a;  wsrl[o] = b;
        }
        if (t < WARM) {                        // window 0 (dummy, seg 0)
            size_t o = (size_t)t * SDIM + i;
            wsgl[o] = a;  wsrl[o] = b;
        }
    }
}

// DPP partial-sum add (row_shr / row_bcast chain; total lands in lane 63)
#define DPP_ADD(S_, CTRL_)                                                     \
{   int t__ = __builtin_amdgcn_update_dpp(0, __builtin_bit_cast(int, (S_)),    \
                                          (CTRL_), 0xF, 0xF, true);            \
    (S_) += __builtin_bit_cast(float, t__); }

// ---------------------------------------------------------------------------
// Fused step: advances TWO independent recurrences (A and B) in one wave.
// ---------------------------------------------------------------------------
#define STEP2(TIA_, TIB_, GLA_, RLA_, RA_, GLB_, RLB_, RB_, DOSTORE_)          \
{                                                                              \
    const int tiA_ = (TIA_);                                                   \
    const int tiB_ = (TIB_);                                                   \
    float rsA_ = __builtin_amdgcn_rcpf(                                        \
                     1.f + __builtin_amdgcn_exp2f(fmaf(rswN, vA, (RLA_))));    \
    float rsB_ = __builtin_amdgcn_rcpf(                                        \
                     1.f + __builtin_amdgcn_exp2f(fmaf(rswN, vB, (RLB_))));    \
    float rvA_ = rsA_ * vA;                                                    \
    float rvB_ = rsB_ * vB;                                                    \
    smA[(half << 6) + i] = half ? rvB_ : rvA_;   /* A->[0..31], B->[64..95] */ \
    __builtin_amdgcn_wave_barrier();                                           \
    float zargA_ = fmaf(gswN, vA, (GLA_));                                     \
    float zargB_ = fmaf(gswN, vB, (GLB_));                                     \
    float hA0_ = b1l, hB0_ = b1l;                                              \
    hA0_ = fmaf(w1r[0], (RA_), hA0_);                                          \
    hB0_ = fmaf(w1r[0], (RB_), hB0_);                                          \
    hA0_ = fmaf(w1r[1], fabsf((RA_)), hA0_);                                   \
    hB0_ = fmaf(w1r[1], fabsf((RB_)), hB0_);                                   \
    hA0_ = fmaf(w1r[2], (RA_) * (RA_), hA0_);                                  \
    hB0_ = fmaf(w1r[2], (RB_) * (RB_), hB0_);                                  \
    float hA1_ = 0.f, hA2_ = 0.f, hA3_ = 0.f;                                  \
    float hB1_ = 0.f, hB2_ = 0.f, hB3_ = 0.f;                                  \
    const float4* rvpA_ = (const float4*)smA;                                  \
    const float4* rvpB_ = (const float4*)(smA + 64);                           \
    _Pragma("unroll")                                                          \
    for (int q_ = 0; q_ < 8; ++q_) {                                           \
        float4 xa_ = rvpA_[q_];                                                \
        float4 xb_ = rvpB_[q_];                                                \
        hA0_ = fmaf(w1r[3 + 4 * q_ + 0], xa_.x, hA0_);                         \
        hB0_ = fmaf(w1r[3 + 4 * q_ + 0], xb_.x, hB0_);                         \
        hA1_ = fmaf(w1r[3 + 4 * q_ + 1], xa_.y, hA1_);                         \
        hB1_ = fmaf(w1r[3 + 4 * q_ + 1], xb_.y, hB1_);                         \
        hA2_ = fmaf(w1r[3 + 4 * q_ + 2], xa_.z, hA2_);                         \
        hB2_ = fmaf(w1r[3 + 4 * q_ + 2], xb_.z, hB2_);                         \
        hA3_ = fmaf(w1r[3 + 4 * q_ + 3], xa_.w, hA3_);                         \
        hB3_ = fmaf(w1r[3 + 4 * q_ + 3], xb_.w, hB3_);                         \
    }                                                                          \
    float hpA_ = (hA0_ + hA1_) + (hA2_ + hA3_);                                \
    float hpB_ = (hB0_ + hB1_) + (hB2_ + hB3_);                                \
    float thA_ = fmaf(-2.f, __builtin_amdgcn_rcpf(                             \
                     __builtin_amdgcn_exp2f(hpA_) + 1.f), 1.f);                \
    float thB_ = fmaf(-2.f, __builtin_amdgcn_rcpf(                             \
                     __builtin_amdgcn_exp2f(hpB_) + 1.f), 1.f);                \
    smB[lane] = thA_;                                                          \
    smB[64 + lane] = thB_;                                                     \
    __builtin_amdgcn_wave_barrier();                                           \
    float zA_ = __builtin_amdgcn_rcpf(1.f + __builtin_amdgcn_exp2f(zargA_));   \
    float zB_ = __builtin_amdgcn_rcpf(1.f + __builtin_amdgcn_exp2f(zargB_));   \
    float qA0_ = 0.f, qA1_ = 0.f, qA2_ = 0.f, qA3_ = 0.f;                      \
    float qB0_ = 0.f, qB1_ = 0.f, qB2_ = 0.f, qB3_ = 0.f;                      \
    const float4* hqA_ = (const float4*)(smB + (half << 5));                   \
    const float4* hqB_ = (const float4*)(smB + 64 + (half << 5));              \
    _Pragma("unroll")                                                          \
    for (int q_ = 0; q_ < 8; ++q_) {                                           \
        float4 ca_ = hqA_[q_];                                                 \
        float4 cb_ = hqB_[q_];                                                 \
        qA0_ = fmaf(w2r[4 * q_ + 0], ca_.x, qA0_);                             \
        qB0_ = fmaf(w2r[4 * q_ + 0], cb_.x, qB0_);                             \
        qA1_ = fmaf(w2r[4 * q_ + 1], ca_.y, qA1_);                             \
        qB1_ = fmaf(w2r[4 * q_ + 1], cb_.y, qB1_);                             \
        qA2_ = fmaf(w2r[4 * q_ + 2], ca_.z, qA2_);                             \
        qB2_ = fmaf(w2r[4 * q_ + 2], cb_.z, qB2_);                             \
        qA3_ = fmaf(w2r[4 * q_ + 3], ca_.w, qA3_);                             \
        qB3_ = fmaf(w2r[4 * q_ + 3], cb_.w, qB3_);                             \
    }                                                                          \
    float pA_ = (qA0_ + qA1_) + (qA2_ + qA3_);                                 \
    float pB_ = (qB0_ + qB1_) + (qB2_ + qB3_);                                 \
    pA_ += __shfl_xor(pA_, 32);                                                \
    pB_ += __shfl_xor(pB_, 32);                                                \
    float rawA_ = pA_ + b2l;                                                   \
    float rawB_ = pB_ + b2l;                                                   \
    float eA_ = __builtin_amdgcn_exp2f(-fabsf(rawA_));                         \
    float eB_ = __builtin_amdgcn_exp2f(-fabsf(rawB_));                         \
    float spA_ = fmaxf(rawA_, 0.f) + __builtin_amdgcn_logf(1.f + eA_);         \
    float spB_ = fmaxf(rawB_, 0.f) + __builtin_amdgcn_logf(1.f + eB_);         \
    float candA_ = LN2 * spA_;                                                 \
    float candB_ = LN2 * spB_;                                                 \
    float vnA_ = fmaxf(fmaf(zA_, candA_ - vA, vA), EPSV);                      \
    float vnB_ = fmaxf(fmaf(zB_, candB_ - vB, vB), EPSV);                      \
    if (DOSTORE_) {                                                            \
        out_z  [(size_t)tiA_ * SDIM + i] = zA_;                                \
        out_cand[(size_t)tiA_ * SDIM + i] = candA_;                            \
        out_z  [(size_t)tiB_ * SDIM + i] = zB_;                                \
        out_cand[(size_t)tiB_ * SDIM + i] = candB_;                            \
        float sA_ = vnA_, sB_ = vnB_;                                          \
        DPP_ADD(sA_, 0x111) DPP_ADD(sA_, 0x112) DPP_ADD(sA_, 0x114)            \
        DPP_ADD(sA_, 0x118) DPP_ADD(sA_, 0x142) DPP_ADD(sA_, 0x143)            \
        DPP_ADD(sB_, 0x111) DPP_ADD(sB_, 0x112) DPP_ADD(sB_, 0x114)            \
        DPP_ADD(sB_, 0x118) DPP_ADD(sB_, 0x142) DPP_ADD(sB_, 0x143)            \
        if (lane == 63) {                                                      \
            out_sigma[tiA_] = sA_ * (1.f / 64.f);                              \
            out_sigma[tiB_] = sB_ * (1.f / 64.f);                              \
        }                                                                      \
    }                                                                          \
    vA = vnA_;                                                                 \
    vB = vnB_;                                                                 \
}

// 4-deep software-pipelined dual-segment run. Slot k refilled (step s+k+4)
// right before consumption -> ~4 fused-steps of load-latency cover.
#define PIPE2(GA_, LA_, RA_, GB_, LB_, RB_, NSTEPS_, TA_, TB_, DOSTORE_)       \
{                                                                              \
    float gA0_, gA1_, gA2_, gA3_, lA0_, lA1_, lA2_, lA3_,                      \
          rA0_, rA1_, rA2_, rA3_;                                              \
    float gB0_, gB1_, gB2_, gB3_, lB0_, lB1_, lB2_, lB3_,                      \
          rB0_, rB1_, rB2_, rB3_;                                              \
    gA0_=(GA_)[0*SDIM+i]; lA0_=(LA_)[0*SDIM+i]; rA0_=(RA_)[0];                 \
    gB0_=(GB_)[0*SDIM+i]; lB0_=(LB_)[0*SDIM+i]; rB0_=(RB_)[0];                 \
    gA1_=(GA_)[1*SDIM+i]; lA1_=(LA_)[1*SDIM+i]; rA1_=(RA_)[1];                 \
    gB1_=(GB_)[1*SDIM+i]; lB1_=(LB_)[1*SDIM+i]; rB1_=(RB_)[1];                 \
    gA2_=(GA_)[2*SDIM+i]; lA2_=(LA_)[2*SDIM+i]; rA2_=(RA_)[2];                 \
    gB2_=(GB_)[2*SDIM+i]; lB2_=(LB_)[2*SDIM+i]; rB2_=(RB_)[2];                 \
    gA3_=(GA_)[3*SDIM+i]; lA3_=(LA_)[3*SDIM+i]; rA3_=(RA_)[3];                 \
    gB3_=(GB_)[3*SDIM+i]; lB3_=(LB_)[3*SDIM+i]; rB3_=(RB_)[3];                 \
    for (int s_ = 0; s_ < (NSTEPS_); s_ += 4) {                                \
        int t0_ = s_ + 4; if (t0_ > (NSTEPS_) - 1) t0_ = (NSTEPS_) - 1;        \
        float cgA_=gA0_, clA_=lA0_, crA_=rA0_;                                 \
        float cgB_=gB0_, clB_=lB0_, crB_=rB0_;                                 \
        gA0_=(GA_)[(size_t)t0_*SDIM+i]; lA0_=(LA_)[(size_t)t0_*SDIM+i];        \
        rA0_=(RA_)[t0_];                                                       \
        gB0_=(GB_)[(size_t)t0_*SDIM+i]; lB0_=(LB_)[(size_t)t0_*SDIM+i];        \
        rB0_=(RB_)[t0_];                                                       \
        STEP2((TA_)+s_+0, (TB_)+s_+0, cgA_, clA_, crA_, cgB_, clB_, crB_,      \
              DOSTORE_)                                                        \
        int t1_ = s_ + 5; if (t1_ > (NSTEPS_) - 1) t1_ = (NSTEPS_) - 1;        \
        cgA_=gA1_; clA_=lA1_; crA_=rA1_;                                       \
        cgB_=gB1_; clB_=lB1_; crB_=rB1_;                                       \
        gA1_=(GA_)[(size_t)t1_*SDIM+i]; lA1_=(LA_)[(size_t)t1_*SDIM+i];        \
        rA1_=(RA_)[t1_];                                                       \
        gB1_=(GB_)[(size_t)t1_*SDIM+i]; lB1_=(LB_)[(size_t)t1_*SDIM+i];        \
        rB1_=(RB_)[t1_];                                                       \
        STEP2((TA_)+s_+1, (TB_)+s_+1, cgA_, clA_, crA_, cgB_, clB_, crB_,      \
              DOSTORE_)                                                        \
        int t2_ = s_ + 6; if (t2_ > (NSTEPS_) - 1) t2_ = (NSTEPS_) - 1;        \
        cgA_=gA2_; clA_=lA2_; crA_=rA2_;                                       \
        cgB_=gB2_; clB_=lB2_; crB_=rB2_;                                       \
        gA2_=(GA_)[(size_t)t2_*SDIM+i]; lA2_=(LA_)[(size_t)t2_*SDIM+i];        \
        rA2_=(RA_)[t2_];                                                       \
        gB2_=(GB_)[(size_t)t2_*SDIM+i]; lB2_=(LB_)[(size_t)t2_*SDIM+i];        \
        rB2_=(RB_)[t2_];                                                       \
        STEP2((TA_)+s_+2, (TB_)+s_+2, cgA_, clA_, crA_, cgB_, clB_, crB_,      \
              DOSTORE_)                                                        \
        int t3_ = s_ + 7; if (t3_ > (NSTEPS_) - 1) t3_ = (NSTEPS_) - 1;        \
        cgA_=gA3_; clA_=lA3_; crA_=rA3_;                                       \
        cgB_=gB3_; clB_=lB3_; crB_=rB3_;                                       \
        gA3_=(GA_)[(size_t)t3_*SDIM+i]; lA3_=(LA_)[(size_t)t3_*SDIM+i];        \
        rA3_=(RA_)[t3_];                                                       \
        gB3_=(GB_)[(size_t)t3_*SDIM+i]; lB3_=(LB_)[(size_t)t3_*SDIM+i];        \
        rB3_=(RB_)[t3_];                                                       \
        STEP2((TA_)+s_+3, (TB_)+s_+3, cgA_, clA_, crA_, cgB_, clB_, crB_,      \
              DOSTORE_)                                                        \
    }                                                                          \
}

// ---------------------------------------------------------------------------
// Kernel 2: speculative-parallel scan, TWO segments per wave (A=2b, B=2b+1).
// amdgpu_waves_per_eu(1, 1): MAX=1 caps occupancy -> 512-VGPR allocation
// budget, so weights + prefetch queues stay register-resident (the (min)-only
// form in r8 left the default 8-wave/EU ~64-reg budget -> per-step L1
// reloads; that was the 1850-2000 cy/step pathology).
// ---------------------------------------------------------------------------
__global__ void __launch_bounds__(64)
__attribute__((amdgpu_waves_per_eu(1, 1)))
scan_kernel(const float* __restrict__ returns,
            const float* __restrict__ gsw,
            const float* __restrict__ rsw,
            const float* __restrict__ W1,     // [64, 35]
            const float* __restrict__ b1,     // [64]
            const float* __restrict__ W2,     // [32, 64]
            const float* __restrict__ b2,     // [32]
            const float* __restrict__ X,      // fallback warm-up only
            const float* __restrict__ gb,
            const float* __restrict__ rg,
            const float* __restrict__ wsgl,   // warm windows (or null)
            const float* __restrict__ wsrl,
            float* __restrict__ out_sigma,    // [N]
            float* __restrict__ out_z,        // [N*32]  (pre-filled glN)
            float* __restrict__ out_cand,     // [N*32]  (pre-filled rlN)
            float* __restrict__ out_vfinal)   // [32]
{
    const int lane = threadIdx.x;
    const int i    = lane & 31;
    const int half = lane >> 5;
    const int bid  = blockIdx.x;
    const int tA   = (2 * bid) * SEG;
    const int tB   = tA + SEG;
    const int wstA = (tA == 0) ? 0 : (tA - WARM);
    const int wstB = tB - WARM;

    __shared__ __align__(16) float smA[128];
    __shared__ __align__(16) float smB[128];
    __shared__ __align__(16) float smGB[32 * 32];   // fallback only
    __shared__ __align__(16) float smRG[32 * 32];   // fallback only

    // ---- static weights, pre-scaled so every transcendental is exp2/log2 ----
    float gswN = -L2E * gsw[i];
    float rswN = -L2E * rsw[i];
    float w1r[35];
#pragma unroll
    for (int j = 0; j < 35; ++j) w1r[j] = (2.f * L2E) * W1[lane * 35 + j];
    float b1l = (2.f * L2E) * b1[lane];
    float w2r[32];                       // half-dot: cols (half*32)..+31
#pragma unroll
    for (int j = 0; j < 32; ++j) w2r[j] = L2E * W2[i * 64 + (half << 5) + j];
    float b2l = L2E * b2[i];

    // pin weights into VGPRs (asm-defined values cannot be rematerialized)
    PIN(gswN); PIN(rswN); PIN(b1l); PIN(b2l);
#pragma unroll
    for (int j = 0; j < 35; ++j) PIN(w1r[j]);
#pragma unroll
    for (int j = 0; j < 32; ++j) PIN(w2r[j]);

    // ---- initial states (warm-start guesses; converge during warm-up) ----
    float rA0 = returns[wstA];
    float rB0 = returns[wstB];
    float vA = rA0 * rA0;
    float vB = rB0 * rB0;

    // ---- warm-up (both segments fused) ----
    if (wsgl) {
        const float* gwA = wsgl + (size_t)(2 * bid) * WARM * SDIM;
        const float* lwA = wsrl + (size_t)(2 * bid) * WARM * SDIM;
        const float* gwB = wsgl + (size_t)(2 * bid + 1) * WARM * SDIM;
        const float* lwB = wsrl + (size_t)(2 * bid + 1) * WARM * SDIM;
        const float* rrA = returns + wstA;
        const float* rrB = returns + wstB;
        PIPE2(gwA, lwA, rrA, gwB, lwB, rrB, WARM, 0, 0, false)
    } else {
        // cold fallback: stage scaled betas in LDS, recompute gl/rl from X
        for (int k = lane; k < 1024; k += 64) {
            smGB[k] = -L2E * gb[k];
            smRG[k] = -L2E * rg[k];
        }
        __syncthreads();
        for (int t = 0; t < WARM; ++t) {
            const float* xA = X + (size_t)(wstA + t) * 32;
            const float* xB = X + (size_t)(wstB + t) * 32;
            float aA = 0.f, cA = 0.f, aB = 0.f, cB = 0.f;
#pragma unroll
            for (int j = 0; j < 32; ++j) {
                float xa = xA[j], xb = xB[j];
                float g_ = smGB[j * 32 + i], r_ = smRG[j * 32 + i];
                aA = fmaf(xa, g_, aA);
                cA = fmaf(xa, r_, cA);
                aB = fmaf(xb, g_, aB);
                cB = fmaf(xb, r_, cB);
            }
            float rca = returns[wstA + t], rcb = returns[wstB + t];
            STEP2(0, 0, aA, cA, rca, aB, cB, rcb, false)
        }
    }

    // segment A of block 0 starts exactly (dummy warm-up discarded)
    if (tA == 0) {
        float r0 = returns[0];
        vA = r0 * r0;
    }

    // ---- owned segments (reads clamped to own range; overwrite in place) ----
    {
        const float* gsA = out_z   + (size_t)tA * SDIM;
        const float* lsA = out_cand + (size_t)tA * SDIM;
        const float* rsA = returns + tA;
        const float* gsB = out_z   + (size_t)tB * SDIM;
        const float* lsB = out_cand + (size_t)tB * SDIM;
        const float* rsB = returns + tB;
        PIPE2(gsA, lsA, rsA, gsB, lsB, rsB, SEG, tA, tB, true)
    }

    if (bid == NSEG / 2 - 1 && lane < SDIM) out_vfinal[i] = vB;
}

// ---------------------------------------------------------------------------
extern "C" void kernel_launch(void* const* d_in, const int* in_sizes, int n_in,
                              void* d_out, int out_size, void* d_ws, size_t ws_size,
                              hipStream_t stream)
{
    const float* X          = (const float*)d_in[0];
    const float* returns    = (const float*)d_in[1];
    const float* gate_beta  = (const float*)d_in[2];
    const float* gsw        = (const float*)d_in[3];
    const float* reset_gamma= (const float*)d_in[4];
    const float* rsw        = (const float*)d_in[5];
    const float* W1         = (const float*)d_in[6];
    const float* b1         = (const float*)d_in[7];
    const float* W2         = (const float*)d_in[8];
    const float* b2         = (const float*)d_in[9];

    float* out       = (float*)d_out;
    float* out_sigma = out;                                   // [N]
    float* out_z     = out + NT;                              // [N*S]
    float* out_cand  = out + NT + (size_t)NT * SDIM;          // [N*S]
    float* out_vfin  = out + NT + 2 * (size_t)NT * SDIM;      // [S]

    const bool use_ws = (ws_size >= WS_NEEDED);
    float* wsgl = use_ws ? (float*)d_ws : nullptr;
    float* wsrl = use_ws ? ((float*)d_ws + WSW) : nullptr;

    precompute_lin<<<(NT * SDIM) / 256, 256, 0, stream>>>(
        X, gate_beta, reset_gamma, out_z, out_cand, wsgl, wsrl);

    scan_kernel<<<NSEG / 2, 64, 0, stream>>>(
        returns, gsw, rsw, W1, b1, W2, b2,
        X, gate_beta, reset_gamma, wsgl, wsrl,
        out_sigma, out_z, out_cand, out_vfin);
}

// Round 10
// 215.945 us; speedup vs baseline: 2.0857x; 1.2326x over previous
//
#include <hip/hip_runtime.h>

#define NT    262144
#define SDIM  32
#define NSEG  4096           // speculative segments; one WAVE runs FOUR chains
#define SEG   (NT / NSEG)    // 64 steps per segment
#define WARM  48             // warm-up steps; WARM < SEG => warm windows disjoint
#define NBLK  (NSEG / 4)     // 1024 blocks
#define EPSV  1e-12f
#define L2E   1.4426950408889634f   // log2(e)
#define LN2   0.6931471805599453f
// warm-window copies in d_ws: NSEG windows (window 0 = dummy) of WARM x 32
#define WSW   ((size_t)NSEG * WARM * SDIM)
#define WS_NEEDED (2 * WSW * 4)     // 50.3 MB, same as rounds 6-9 (proven)

#define PIN(X_) asm volatile("" : "+v"(X_))

// ---------------------------------------------------------------------------
// Kernel 1: gl/rl precompute (pre-negated-scaled for exp2 sigmoids) + compact
// warm-window copies. Each thread computes TWO t-rows (t and t+NT/2) to
// amortize beta loads; X read as float4.
// ---------------------------------------------------------------------------
__global__ void precompute_lin(const float* __restrict__ X,
                               const float* __restrict__ gb,
                               const float* __restrict__ rg,
                               float* __restrict__ glN,
                               float* __restrict__ rlN,
                               float* __restrict__ wsgl,   // may be null
                               float* __restrict__ wsrl)
{
    int idx = blockIdx.x * blockDim.x + threadIdx.x;   // covers (NT/2)*32
    int t0 = idx >> 5, i = idx & 31;
    int t1 = t0 + NT / 2;
    const float4* xr0 = (const float4*)(X + (size_t)t0 * 32);
    const float4* xr1 = (const float4*)(X + (size_t)t1 * 32);
    float a0 = 0.f, c0 = 0.f, a1 = 0.f, c1 = 0.f;
#pragma unroll
    for (int q = 0; q < 8; ++q) {
        float4 x0 = xr0[q], x1 = xr1[q];
#pragma unroll
        for (int u = 0; u < 4; ++u) {
            int j = 4 * q + u;
            float gv = gb[j * 32 + i], rv = rg[j * 32 + i];
            float xe0 = (u == 0) ? x0.x : (u == 1) ? x0.y : (u == 2) ? x0.z : x0.w;
            float xe1 = (u == 0) ? x1.x : (u == 1) ? x1.y : (u == 2) ? x1.z : x1.w;
            a0 = fmaf(xe0, gv, a0);  c0 = fmaf(xe0, rv, c0);
            a1 = fmaf(xe1, gv, a1);  c1 = fmaf(xe1, rv, c1);
        }
    }
    a0 *= -L2E; c0 *= -L2E; a1 *= -L2E; c1 *= -L2E;
    glN[(size_t)t0 * 32 + i] = a0;  rlN[(size_t)t0 * 32 + i] = c0;
    glN[(size_t)t1 * 32 + i] = a1;  rlN[(size_t)t1 * 32 + i] = c1;
    if (wsgl) {
#pragma unroll
        for (int u = 0; u < 2; ++u) {
            int t = u ? t1 : t0;
            float a = u ? a1 : a0, c = u ? c1 : c0;
            int m  = t % SEG;
            int s1 = t / SEG + 1;
            if (m >= SEG - WARM && s1 < NSEG) {
                size_t o = ((size_t)s1 * WARM + (m - (SEG - WARM))) * SDIM + i;
                wsgl[o] = a;  wsrl[o] = c;
            }
            if (t < WARM) {                    // window 0 (dummy, seg 0)
                size_t o = (size_t)t * SDIM + i;
                wsgl[o] = a;  wsrl[o] = c;
            }
        }
    }
}

// DPP partial-sum: after 4 row_shr + row_bcast15, lane31 = sum(lanes 0..31),
// lane63 = sum(lanes 32..63).
#define DPP_ADD(S_, CTRL_)                                                     \
{   int t__ = __builtin_amdgcn_update_dpp(0, __builtin_bit_cast(int, (S_)),    \
                                          (CTRL_), 0xF, 0xF, true);            \
    (S_) += __builtin_bit_cast(float, t__); }
#define HALFSUM(S_)                                                            \
    DPP_ADD(S_, 0x111) DPP_ADD(S_, 0x112) DPP_ADD(S_, 0x114)                   \
    DPP_ADD(S_, 0x118) DPP_ADD(S_, 0x142)

// ---------------------------------------------------------------------------
// STEP4: advance 4 chains (pairs (A,B),(C,D); within a pair, chain state is
// half-split: lanes 0-31 hold A(C), lanes 32-63 hold B(D)). Gates, updates,
// z/cand stores, sigma reductions are computed ONCE per pair (64-wide covers
// both chains); only the W1/W2 matvecs are per-chain (irreducible).
// ---------------------------------------------------------------------------
#define STEP4(TIA_, TIB_, TIC_, TID_, G1_, L1_, G2_, L2_, RA_, RB_, RC_, RD_, DOSTORE_) \
{                                                                              \
    const int tiA_ = (TIA_); const int tiB_ = (TIB_);                          \
    const int tiC_ = (TIC_); const int tiD_ = (TID_);                          \
    float rs1_ = __builtin_amdgcn_rcpf(                                        \
                     1.f + __builtin_amdgcn_exp2f(fmaf(rswN, v1, (L1_))));     \
    float rs2_ = __builtin_amdgcn_rcpf(                                        \
                     1.f + __builtin_amdgcn_exp2f(fmaf(rswN, v2, (L2_))));     \
    smA[lane] = rs1_ * v1;           /* A -> [0:32], B -> [32:64] */           \
    smA[64 + lane] = rs2_ * v2;      /* C -> [64:96], D -> [96:128] */         \
    __builtin_amdgcn_wave_barrier();                                           \
    float zg1_ = fmaf(gswN, v1, (G1_));                                        \
    float zg2_ = fmaf(gswN, v2, (G2_));                                        \
    float hA0_ = b1l, hB0_ = b1l, hC0_ = b1l, hD0_ = b1l;                      \
    hA0_ = fmaf(w1r[0], (RA_), hA0_);  hB0_ = fmaf(w1r[0], (RB_), hB0_);       \
    hC0_ = fmaf(w1r[0], (RC_), hC0_);  hD0_ = fmaf(w1r[0], (RD_), hD0_);       \
    float hA1_ = w1r[1] * fabsf((RA_)), hB1_ = w1r[1] * fabsf((RB_));          \
    float hC1_ = w1r[1] * fabsf((RC_)), hD1_ = w1r[1] * fabsf((RD_));          \
    hA0_ = fmaf(w1r[2], (RA_) * (RA_), hA0_);                                  \
    hB0_ = fmaf(w1r[2], (RB_) * (RB_), hB0_);                                  \
    hC0_ = fmaf(w1r[2], (RC_) * (RC_), hC0_);                                  \
    hD0_ = fmaf(w1r[2], (RD_) * (RD_), hD0_);                                  \
    {                                                                          \
        const float4* pA_ = (const float4*)smA;                                \
        const float4* pB_ = (const float4*)(smA + 32);                         \
        const float4* pC_ = (const float4*)(smA + 64);                         \
        const float4* pD_ = (const float4*)(smA + 96);                         \
        _Pragma("unroll")                                                      \
        for (int q_ = 0; q_ < 8; ++q_) {                                       \
            float4 xa_ = pA_[q_], xb_ = pB_[q_], xc_ = pC_[q_], xd_ = pD_[q_]; \
            hA0_ = fmaf(w1r[3 + 4 * q_ + 0], xa_.x, hA0_);                     \
            hA1_ = fmaf(w1r[3 + 4 * q_ + 1], xa_.y, hA1_);                     \
            hA0_ = fmaf(w1r[3 + 4 * q_ + 2], xa_.z, hA0_);                     \
            hA1_ = fmaf(w1r[3 + 4 * q_ + 3], xa_.w, hA1_);                     \
            hB0_ = fmaf(w1r[3 + 4 * q_ + 0], xb_.x, hB0_);                     \
            hB1_ = fmaf(w1r[3 + 4 * q_ + 1], xb_.y, hB1_);                     \
            hB0_ = fmaf(w1r[3 + 4 * q_ + 2], xb_.z, hB0_);                     \
            hB1_ = fmaf(w1r[3 + 4 * q_ + 3], xb_.w, hB1_);                     \
            hC0_ = fmaf(w1r[3 + 4 * q_ + 0], xc_.x, hC0_);                     \
            hC1_ = fmaf(w1r[3 + 4 * q_ + 1], xc_.y, hC1_);                     \
            hC0_ = fmaf(w1r[3 + 4 * q_ + 2], xc_.z, hC0_);                     \
            hC1_ = fmaf(w1r[3 + 4 * q_ + 3], xc_.w, hC1_);                     \
            hD0_ = fmaf(w1r[3 + 4 * q_ + 0], xd_.x, hD0_);                     \
            hD1_ = fmaf(w1r[3 + 4 * q_ + 1], xd_.y, hD1_);                     \
            hD0_ = fmaf(w1r[3 + 4 * q_ + 2], xd_.z, hD0_);                     \
            hD1_ = fmaf(w1r[3 + 4 * q_ + 3], xd_.w, hD1_);                     \
        }                                                                      \
    }                                                                          \
    float thA_ = fmaf(-2.f, __builtin_amdgcn_rcpf(                             \
                   __builtin_amdgcn_exp2f(hA0_ + hA1_) + 1.f), 1.f);           \
    float thB_ = fmaf(-2.f, __builtin_amdgcn_rcpf(                             \
                   __builtin_amdgcn_exp2f(hB0_ + hB1_) + 1.f), 1.f);           \
    float thC_ = fmaf(-2.f, __builtin_amdgcn_rcpf(                             \
                   __builtin_amdgcn_exp2f(hC0_ + hC1_) + 1.f), 1.f);           \
    float thD_ = fmaf(-2.f, __builtin_amdgcn_rcpf(                             \
                   __builtin_amdgcn_exp2f(hD0_ + hD1_) + 1.f), 1.f);           \
    smB[lane] = thA_;  smB[64 + lane] = thB_;                                  \
    smB[128 + lane] = thC_;  smB[192 + lane] = thD_;                           \
    __builtin_amdgcn_wave_barrier();                                           \
    float z1_ = __builtin_amdgcn_rcpf(1.f + __builtin_amdgcn_exp2f(zg1_));     \
    float z2_ = __builtin_amdgcn_rcpf(1.f + __builtin_amdgcn_exp2f(zg2_));     \
    float q1a_ = 0.f, q1b_ = 0.f, q1c_ = 0.f, q1d_ = 0.f;                      \
    float q2a_ = 0.f, q2b_ = 0.f, q2c_ = 0.f, q2d_ = 0.f;                      \
    {                                                                          \
        const float4* p1_ = (const float4*)(smB + (half << 6));                \
        const float4* p2_ = (const float4*)(smB + 128 + (half << 6));          \
        _Pragma("unroll")                                                      \
        for (int q_ = 0; q_ < 16; ++q_) {                                      \
            float4 c1_ = p1_[q_];                                              \
            q1a_ = fmaf(w2r[4 * q_ + 0], c1_.x, q1a_);                         \
            q1b_ = fmaf(w2r[4 * q_ + 1], c1_.y, q1b_);                         \
            q1c_ = fmaf(w2r[4 * q_ + 2], c1_.z, q1c_);                         \
            q1d_ = fmaf(w2r[4 * q_ + 3], c1_.w, q1d_);                         \
            float4 c2_ = p2_[q_];                                              \
            q2a_ = fmaf(w2r[4 * q_ + 0], c2_.x, q2a_);                         \
            q2b_ = fmaf(w2r[4 * q_ + 1], c2_.y, q2b_);                         \
            q2c_ = fmaf(w2r[4 * q_ + 2], c2_.z, q2c_);                         \
            q2d_ = fmaf(w2r[4 * q_ + 3], c2_.w, q2d_);                         \
        }                                                                      \
    }                                                                          \
    float raw1_ = ((q1a_ + q1b_) + (q1c_ + q1d_)) + b2l;                       \
    float raw2_ = ((q2a_ + q2b_) + (q2c_ + q2d_)) + b2l;                       \
    float e1_ = __builtin_amdgcn_exp2f(-fabsf(raw1_));                         \
    float e2_ = __builtin_amdgcn_exp2f(-fabsf(raw2_));                         \
    float cand1_ = LN2 * (fmaxf(raw1_, 0.f) + __builtin_amdgcn_logf(1.f + e1_)); \
    float cand2_ = LN2 * (fmaxf(raw2_, 0.f) + __builtin_amdgcn_logf(1.f + e2_)); \
    float vn1_ = fmaxf(fmaf(z1_, cand1_ - v1, v1), EPSV);                      \
    float vn2_ = fmaxf(fmaf(z2_, cand2_ - v2, v2), EPSV);                      \
    if (DOSTORE_) {                                                            \
        out_z  [(size_t)(half ? tiB_ : tiA_) * SDIM + i] = z1_;                \
        out_cand[(size_t)(half ? tiB_ : tiA_) * SDIM + i] = cand1_;            \
        out_z  [(size_t)(half ? tiD_ : tiC_) * SDIM + i] = z2_;                \
        out_cand[(size_t)(half ? tiD_ : tiC_) * SDIM + i] = cand2_;            \
        float s1_ = vn1_, s2_ = vn2_;                                          \
        HALFSUM(s1_) HALFSUM(s2_)                                              \
        if ((lane & 31) == 31) {                                               \
            out_sigma[half ? tiB_ : tiA_] = s1_ * (1.f / 32.f);                \
            out_sigma[half ? tiD_ : tiC_] = s2_ * (1.f / 32.f);                \
        }                                                                      \
    }                                                                          \
    v1 = vn1_;                                                                 \
    v2 = vn2_;                                                                 \
}

// 4-deep pipelined quad-segment run. gl/rl pointers are PER-LANE (half-split:
// lane's pointer already selects its chain). r is loaded float4 per chain per
// 4-step group (wave-uniform).
#define PIPE4(G1P_, L1P_, G2P_, L2P_, RAP_, RBP_, RCP_, RDP_, NSTEPS_,         \
              TA_, TB_, TC_, TD_, DOSTORE_)                                    \
{                                                                              \
    float g1q0_, g1q1_, g1q2_, g1q3_, l1q0_, l1q1_, l1q2_, l1q3_;              \
    float g2q0_, g2q1_, g2q2_, g2q3_, l2q0_, l2q1_, l2q2_, l2q3_;              \
    g1q0_=(G1P_)[0*SDIM+i]; l1q0_=(L1P_)[0*SDIM+i];                            \
    g2q0_=(G2P_)[0*SDIM+i]; l2q0_=(L2P_)[0*SDIM+i];                            \
    g1q1_=(G1P_)[1*SDIM+i]; l1q1_=(L1P_)[1*SDIM+i];                            \
    g2q1_=(G2P_)[1*SDIM+i]; l2q1_=(L2P_)[1*SDIM+i];                            \
    g1q2_=(G1P_)[2*SDIM+i]; l1q2_=(L1P_)[2*SDIM+i];                            \
    g2q2_=(G2P_)[2*SDIM+i]; l2q2_=(L2P_)[2*SDIM+i];                            \
    g1q3_=(G1P_)[3*SDIM+i]; l1q3_=(L1P_)[3*SDIM+i];                            \
    g2q3_=(G2P_)[3*SDIM+i]; l2q3_=(L2P_)[3*SDIM+i];                            \
    float4 rA4_ = *(const float4*)(RAP_);                                      \
    float4 rB4_ = *(const float4*)(RBP_);                                      \
    float4 rC4_ = *(const float4*)(RCP_);                                      \
    float4 rD4_ = *(const float4*)(RDP_);                                      \
    for (int s_ = 0; s_ < (NSTEPS_); s_ += 4) {                                \
        int rp_ = s_ + 4; if (rp_ > (NSTEPS_) - 4) rp_ = (NSTEPS_) - 4;        \
        float4 rAn_ = *(const float4*)((RAP_) + rp_);                          \
        float4 rBn_ = *(const float4*)((RBP_) + rp_);                          \
        float4 rCn_ = *(const float4*)((RCP_) + rp_);                          \
        float4 rDn_ = *(const float4*)((RDP_) + rp_);                          \
        int t0_ = s_ + 4; if (t0_ > (NSTEPS_) - 1) t0_ = (NSTEPS_) - 1;        \
        float cg1_=g1q0_, cl1_=l1q0_, cg2_=g2q0_, cl2_=l2q0_;                  \
        g1q0_=(G1P_)[(size_t)t0_*SDIM+i]; l1q0_=(L1P_)[(size_t)t0_*SDIM+i];    \
        g2q0_=(G2P_)[(size_t)t0_*SDIM+i]; l2q0_=(L2P_)[(size_t)t0_*SDIM+i];    \
        STEP4((TA_)+s_+0, (TB_)+s_+0, (TC_)+s_+0, (TD_)+s_+0,                  \
              cg1_, cl1_, cg2_, cl2_, rA4_.x, rB4_.x, rC4_.x, rD4_.x, DOSTORE_)\
        int t1_ = s_ + 5; if (t1_ > (NSTEPS_) - 1) t1_ = (NSTEPS_) - 1;        \
        cg1_=g1q1_; cl1_=l1q1_; cg2_=g2q1_; cl2_=l2q1_;                        \
        g1q1_=(G1P_)[(size_t)t1_*SDIM+i]; l1q1_=(L1P_)[(size_t)t1_*SDIM+i];    \
        g2q1_=(G2P_)[(size_t)t1_*SDIM+i]; l2q1_=(L2P_)[(size_t)t1_*SDIM+i];    \
        STEP4((TA_)+s_+1, (TB_)+s_+1, (TC_)+s_+1, (TD_)+s_+1,                  \
              cg1_, cl1_, cg2_, cl2_, rA4_.y, rB4_.y, rC4_.y, rD4_.y, DOSTORE_)\
        int t2_ = s_ + 6; if (t2_ > (NSTEPS_) - 1) t2_ = (NSTEPS_) - 1;        \
        cg1_=g1q2_; cl1_=l1q2_; cg2_=g2q2_; cl2_=l2q2_;                        \
        g1q2_=(G1P_)[(size_t)t2_*SDIM+i]; l1q2_=(L1P_)[(size_t)t2_*SDIM+i];    \
        g2q2_=(G2P_)[(size_t)t2_*SDIM+i]; l2q2_=(L2P_)[(size_t)t2_*SDIM+i];    \
        STEP4((TA_)+s_+2, (TB_)+s_+2, (TC_)+s_+2, (TD_)+s_+2,                  \
              cg1_, cl1_, cg2_, cl2_, rA4_.z, rB4_.z, rC4_.z, rD4_.z, DOSTORE_)\
        int t3_ = s_ + 7; if (t3_ > (NSTEPS_) - 1) t3_ = (NSTEPS_) - 1;        \
        cg1_=g1q3_; cl1_=l1q3_; cg2_=g2q3_; cl2_=l2q3_;                        \
        g1q3_=(G1P_)[(size_t)t3_*SDIM+i]; l1q3_=(L1P_)[(size_t)t3_*SDIM+i];    \
        g2q3_=(G2P_)[(size_t)t3_*SDIM+i]; l2q3_=(L2P_)[(size_t)t3_*SDIM+i];    \
        STEP4((TA_)+s_+3, (TB_)+s_+3, (TC_)+s_+3, (TD_)+s_+3,                  \
              cg1_, cl1_, cg2_, cl2_, rA4_.w, rB4_.w, rC4_.w, rD4_.w, DOSTORE_)\
        rA4_ = rAn_; rB4_ = rBn_; rC4_ = rCn_; rD4_ = rDn_;                    \
    }                                                                          \
}

// ---------------------------------------------------------------------------
// Kernel 2: speculative-parallel scan, FOUR chains per wave.
// ---------------------------------------------------------------------------
__global__ void __launch_bounds__(64)
__attribute__((amdgpu_waves_per_eu(1, 1)))
scan_kernel(const float* __restrict__ returns,
            const float* __restrict__ gsw,
            const float* __restrict__ rsw,
            const float* __restrict__ W1,     // [64, 35]
            const float* __restrict__ b1,     // [64]
            const float* __restrict__ W2,     // [32, 64]
            const float* __restrict__ b2,     // [32]
            const float* __restrict__ X,      // fallback warm-up only
            const float* __restrict__ gb,
            const float* __restrict__ rg,
            const float* __restrict__ wsgl,   // warm windows (or null)
            const float* __restrict__ wsrl,
            float* __restrict__ out_sigma,    // [N]
            float* __restrict__ out_z,        // [N*32]  (pre-filled glN)
            float* __restrict__ out_cand,     // [N*32]  (pre-filled rlN)
            float* __restrict__ out_vfinal)   // [32]
{
    const int lane = threadIdx.x;
    const int i    = lane & 31;
    const int half = lane >> 5;
    const int bid  = blockIdx.x;
    const int tA   = (4 * bid) * SEG;
    const int tB   = tA + SEG;
    const int tC   = tA + 2 * SEG;
    const int tD   = tA + 3 * SEG;
    const int wstA = (tA == 0) ? 0 : (tA - WARM);
    const int wstB = tB - WARM;
    const int wstC = tC - WARM;
    const int wstD = tD - WARM;

    __shared__ __align__(16) float smA[128];
    __shared__ __align__(16) float smB[256];
    __shared__ __align__(16) float smGB[32 * 32];   // fallback only
    __shared__ __align__(16) float smRG[32 * 32];   // fallback only

    // ---- static weights, pre-scaled so every transcendental is exp2/log2 ----
    float gswN = -L2E * gsw[i];
    float rswN = -L2E * rsw[i];
    float w1r[35];
#pragma unroll
    for (int j = 0; j < 35; ++j) w1r[j] = (2.f * L2E) * W1[lane * 35 + j];
    float b1l = (2.f * L2E) * b1[lane];
    float w2r[64];                       // FULL row i (both pairs use row i)
#pragma unroll
    for (int j = 0; j < 64; ++j) w2r[j] = L2E * W2[i * 64 + j];
    float b2l = L2E * b2[i];

    PIN(gswN); PIN(rswN); PIN(b1l); PIN(b2l);
#pragma unroll
    for (int j = 0; j < 35; ++j) PIN(w1r[j]);
#pragma unroll
    for (int j = 0; j < 64; ++j) PIN(w2r[j]);

    // ---- initial states: half-split (pair1 = A|B, pair2 = C|D) ----
    float r10 = returns[half ? wstB : wstA];
    float r20 = returns[half ? wstD : wstC];
    float v1 = r10 * r10;
    float v2 = r20 * r20;

    // ---- warm-up (all 4 chains fused) ----
    if (wsgl) {
        const float* g1p = wsgl + (size_t)(4 * bid + (half ? 1 : 0)) * WARM * SDIM;
        const float* l1p = wsrl + (size_t)(4 * bid + (half ? 1 : 0)) * WARM * SDIM;
        const float* g2p = wsgl + (size_t)(4 * bid + (half ? 3 : 2)) * WARM * SDIM;
        const float* l2p = wsrl + (size_t)(4 * bid + (half ? 3 : 2)) * WARM * SDIM;
        const float* rAp = returns + wstA;
        const float* rBp = returns + wstB;
        const float* rCp = returns + wstC;
        const float* rDp = returns + wstD;
        PIPE4(g1p, l1p, g2p, l2p, rAp, rBp, rCp, rDp, WARM, 0, 0, 0, 0, false)
    } else {
        // cold fallback (never taken when ws present): recompute gl/rl from X
        for (int k = lane; k < 1024; k += 64) {
            smGB[k] = -L2E * gb[k];
            smRG[k] = -L2E * rg[k];
        }
        __syncthreads();
        for (int t = 0; t < WARM; ++t) {
            const float* x1 = X + (size_t)((half ? wstB : wstA) + t) * 32;
            const float* x2 = X + (size_t)((half ? wstD : wstC) + t) * 32;
            float a1 = 0.f, c1 = 0.f, a2 = 0.f, c2 = 0.f;
#pragma unroll
            for (int j = 0; j < 32; ++j) {
                float g_ = smGB[j * 32 + i], r_ = smRG[j * 32 + i];
                float xe1 = x1[j], xe2 = x2[j];
                a1 = fmaf(xe1, g_, a1);  c1 = fmaf(xe1, r_, c1);
                a2 = fmaf(xe2, g_, a2);  c2 = fmaf(xe2, r_, c2);
            }
            float ra_ = returns[wstA + t], rb_ = returns[wstB + t];
            float rc_ = returns[wstC + t], rd_ = returns[wstD + t];
            STEP4(0, 0, 0, 0, a1, c1, a2, c2, ra_, rb_, rc_, rd_, false)
        }
    }

    // chain A of block 0 starts exactly (its dummy warm-up is discarded)
    if (tA == 0 && half == 0) {
        float r0 = returns[0];
        v1 = r0 * r0;
    }

    // ---- owned segments (reads clamped to own range; overwrite in place) ----
    {
        const float* g1p = out_z   + (size_t)(half ? tB : tA) * SDIM;
        const float* l1p = out_cand + (size_t)(half ? tB : tA) * SDIM;
        const float* g2p = out_z   + (size_t)(half ? tD : tC) * SDIM;
        const float* l2p = out_cand + (size_t)(half ? tD : tC) * SDIM;
        const float* rAp = returns + tA;
        const float* rBp = returns + tB;
        const float* rCp = returns + tC;
        const float* rDp = returns + tD;
        PIPE4(g1p, l1p, g2p, l2p, rAp, rBp, rCp, rDp, SEG, tA, tB, tC, tD, true)
    }

    // final state = end of chain D (half1 pair2 lanes of the last block)
    if (bid == NBLK - 1 && half == 1) out_vfinal[i] = v2;
}

// ---------------------------------------------------------------------------
extern "C" void kernel_launch(void* const* d_in, const int* in_sizes, int n_in,
                              void* d_out, int out_size, void* d_ws, size_t ws_size,
                              hipStream_t stream)
{
    const float* X          = (const float*)d_in[0];
    const float* returns    = (const float*)d_in[1];
    const float* gate_beta  = (const float*)d_in[2];
    const float* gsw        = (const float*)d_in[3];
    const float* reset_gamma= (const float*)d_in[4];
    const float* rsw        = (const float*)d_in[5];
    const float* W1         = (const float*)d_in[6];
    const float* b1         = (const float*)d_in[7];
    const float* W2         = (const float*)d_in[8];
    const float* b2         = (const float*)d_in[9];

    float* out       = (float*)d_out;
    float* out_sigma = out;                                   // [N]
    float* out_z     = out + NT;                              // [N*S]
    float* out_cand  = out + NT + (size_t)NT * SDIM;          // [N*S]
    float* out_vfin  = out + NT + 2 * (size_t)NT * SDIM;      // [S]

    const bool use_ws = (ws_size >= WS_NEEDED);
    float* wsgl = use_ws ? (float*)d_ws : nullptr;
    float* wsrl = use_ws ? ((float*)d_ws + WSW) : nullptr;

    precompute_lin<<<(NT / 2 * SDIM) / 256, 256, 0, stream>>>(
        X, gate_beta, reset_gamma, out_z, out_cand, wsgl, wsrl);

    scan_kernel<<<NBLK, 64, 0, stream>>>(
        returns, gsw, rsw, W1, b1, W2, b2,
        X, gate_beta, reset_gamma, wsgl, wsrl,
        out_sigma, out_z, out_cand, out_vfin);
}